// Round 11
// baseline (51.147 us; speedup 1.0000x reference)
//
#include <hip/hip_runtime.h>
#include <hip/hip_bf16.h>
#include <stdint.h>

typedef __bf16 bf16_t;
typedef __bf16 bf16x8 __attribute__((ext_vector_type(8)));
typedef float  f32x4  __attribute__((ext_vector_type(4)));
typedef float  f32x16 __attribute__((ext_vector_type(16)));
typedef unsigned int uint;
typedef uint uintx4 __attribute__((ext_vector_type(4)));

#define MFMA16(a,b,c) __builtin_amdgcn_mfma_f32_16x16x32_bf16((a),(b),(c),0,0,0)
#define MFMA32(a,b,c) __builtin_amdgcn_mfma_f32_32x32x16_bf16((a),(b),(c),0,0,0)

constexpr int NB = 16;
constexpr int LQ = 8192;
constexpr int LK = 128;
constexpr int H  = 128;

// log2(e) / sqrt(H): fold softmax scale + exp2 conversion into one multiply
constexpr float C1 = 1.4426950408889634f / 11.313708498984761f;

constexpr size_t WS_FLAG = 0;
// per batch 64KB: [M frag-chunks 32KB | V frag-chunks 32KB]
// chunk (t,kt) at offset ((t*8+kt)<<10); entry for lane l at +l*16:
//   M: M[t*32 + (l&31)][kt*16 + (l>>5)*8 + e], e=0..7  (bf16x8)
//   V: V[t*32 + (l&31)][kt*16 + (l>>5)*8 + e]
constexpr size_t WS_MV   = 1024;

// XOR swizzle for [*][128] bf16 LDS tiles (row stride 256 B) — prep only
__device__ __forceinline__ unsigned swz(unsigned row, unsigned byte) {
  return row * 256u + (byte ^ ((row & 15u) << 4));
}

__device__ __forceinline__ bf16x8 cvt_frag(const float* p) {
  f32x4 u0 = *(const f32x4*)p;
  f32x4 u1 = *(const f32x4*)(p + 4);
  bf16x8 v;
  #pragma unroll
  for (int e = 0; e < 4; ++e) { v[e] = (bf16_t)u0[e]; v[e + 4] = (bf16_t)u1[e]; }
  return v;
}

__device__ __forceinline__ f32x16 zero16() {
  f32x16 z;
  #pragma unroll
  for (int i = 0; i < 16; ++i) z[i] = 0.f;
  return z;
}

// v_cvt_pk_bf16_f32: lo = bf16(a), hi = bf16(b)
__device__ __forceinline__ uint pkbf(float a, float b) {
  uint d;
  asm("v_cvt_pk_bf16_f32 %0, %1, %2" : "=v"(d) : "v"(a), "v"(b));
  return d;
}

// ---------------------------------------------------------------------------
// prep (32 blocks): block 2b   -> M_b = x2_b @ (wq^T wk)  (frag-order to ws)
//                   block 2b+1 -> V_b = x2_b @ wv^T       (frag-order to ws)
// Build path (swizzled LDS image) is r8-r10's validated code; a final repack
// pass converts the image to fragment-major chunks in ws.
// ---------------------------------------------------------------------------
__global__ __launch_bounds__(512) void prep_kernel(
    const float* __restrict__ x2, const float* __restrict__ wq,
    const float* __restrict__ wk, const float* __restrict__ wv,
    const unsigned* __restrict__ x3w, uint8_t* __restrict__ ws)
{
  __shared__ uint8_t sP[131072];  // [wqT 32K | wkT 32K | W2T lin 32K | out 32K]
  __shared__ int sF32, sBig;
  const int tid = threadIdx.x;
  const int b = blockIdx.x >> 1, which = blockIdx.x & 1;
  const int l = tid & 63, w = tid >> 6, q31 = l & 31, hi2 = l >> 5;
  uint8_t* sOut = sP + 98304;

  if (which == 0) {
    if (blockIdx.x == 0) {
      // mask dtype probe over first 2048 words of x3:
      // int32 bool -> words in {0,1}; uint8 bool -> words like 0x01010101 (>1);
      // f32 bool -> words in {0, 0x3f800000}
      if (tid == 0) { sF32 = 0; sBig = 0; }
      __syncthreads();
      int f = 0, g = 0;
      #pragma unroll
      for (int j = 0; j < 4; ++j) {
        unsigned v = x3w[tid * 4 + j];
        if (v == 0x3f800000u) f = 1;
        else if (v > 1u) g = 1;
      }
      if (f) sF32 = 1;
      if (g) sBig = 1;
      __syncthreads();
      if (tid == 0) *(int*)(ws + WS_FLAG) = (sF32 == 0 && sBig == 1) ? 1 : 0;
    }

    // stage wqT / wkT swizzled
    {
      const int row = tid >> 2, c0 = (tid & 3) * 32;
      #pragma unroll
      for (int wh = 0; wh < 2; ++wh) {
        const float* W = wh ? wk : wq;
        uint8_t* dst = sP + wh * 32768;
        const float* s = W + row * H + c0;
        #pragma unroll
        for (int j = 0; j < 32; ++j)
          *(bf16_t*)(dst + swz(c0 + j, row * 2)) = (bf16_t)s[j];
      }
    }
    __syncthreads();

    // W2T[i][j] = sum_k wq[k][i] wk[k][j]  -> LDS linear [128][128] bf16
    {
      const int lo = l & 15, hi = l >> 4;
      bf16x8 a4[4];
      #pragma unroll
      for (int kk = 0; kk < 4; ++kk)
        a4[kk] = *(const bf16x8*)(sP + swz(16 * w + lo, kk * 64 + hi * 16));
      bf16_t* W2T = (bf16_t*)(sP + 65536);
      #pragma unroll
      for (int t = 0; t < 8; ++t) {
        f32x4 c = {0.f, 0.f, 0.f, 0.f};
        #pragma unroll
        for (int kk = 0; kk < 4; ++kk)
          c = MFMA16(a4[kk], *(const bf16x8*)(sP + 32768 + swz(16 * t + lo, kk * 64 + hi * 16)), c);
        #pragma unroll
        for (int r = 0; r < 4; ++r)
          W2T[(16 * w + hi * 4 + r) * H + 16 * t + lo] = (bf16_t)c[r];
      }
    }
    __syncthreads();

    // M build
    if (w < 4) {
      const int wb = w;
      bf16x8 axf[8];
      const float* x2r = x2 + ((size_t)b * LK + 32 * wb + q31) * H;
      #pragma unroll
      for (int kt = 0; kt < 8; ++kt)
        axf[kt] = cvt_frag(x2r + kt * 16 + 8 * hi2);
      const bf16_t* W2Tl = (const bf16_t*)(sP + 65536);
      #pragma unroll
      for (int nt = 0; nt < 4; ++nt) {
        f32x16 c = zero16();
        #pragma unroll
        for (int kt = 0; kt < 8; ++kt)
          c = MFMA32(axf[kt],
                     *(const bf16x8*)(W2Tl + (size_t)(nt * 32 + q31) * H + kt * 16 + 8 * hi2), c);
        #pragma unroll
        for (int r = 0; r < 16; ++r)
          *(bf16_t*)(sOut + swz(32 * wb + (r & 3) + 8 * (r >> 2) + 4 * hi2,
                                (nt * 32 + q31) * 2)) = (bf16_t)c[r];
      }
    }
  } else {
    // V build
    if (w < 4) {
      const int wb = w;
      bf16x8 axf[8];
      const float* x2r = x2 + ((size_t)b * LK + 32 * wb + q31) * H;
      #pragma unroll
      for (int kt = 0; kt < 8; ++kt)
        axf[kt] = cvt_frag(x2r + kt * 16 + 8 * hi2);
      #pragma unroll
      for (int nt = 0; nt < 4; ++nt) {
        f32x16 c = zero16();
        #pragma unroll
        for (int kt = 0; kt < 8; ++kt)
          c = MFMA32(axf[kt],
                     cvt_frag(wv + (size_t)(nt * 32 + q31) * H + kt * 16 + 8 * hi2), c);
        #pragma unroll
        for (int r = 0; r < 16; ++r)
          *(bf16_t*)(sOut + swz(32 * wb + (r & 3) + 8 * (r >> 2) + 4 * hi2,
                                (nt * 32 + q31) * 2)) = (bf16_t)c[r];
      }
    }
  }
  __syncthreads();

  // repack swizzled image -> fragment-major chunks in ws.
  // 32 chunks x 64 entries x 16B = 32KB; idx = entry id.
  {
    uint8_t* dst = ws + WS_MV + (size_t)b * 65536 + (size_t)which * 32768;
    #pragma unroll
    for (int pass = 0; pass < 4; ++pass) {
      const int idx = tid + pass * 512;         // 0..2047
      const int chunk = idx >> 6, le = idx & 63;
      const int t4 = chunk >> 3, kt = chunk & 7;
      bf16x8 v = *(const bf16x8*)(sOut + swz(t4 * 32 + (le & 31),
                                             kt * 32 + (le >> 5) * 16));
      *(bf16x8*)(dst + (size_t)idx * 16) = v;
    }
  }
}

// ---------------------------------------------------------------------------
// Main fused kernel — "frag-stream": NO LDS, NO barriers.
// Block = 256 threads = 4 independent waves; each wave owns one 32-q-row
// subtile. Grid 1024 (16 b x 64 chunks of 128 rows). B-operand fragments for
// both GEMMs are read as perfectly-coalesced dwordx4 streams from the L2-hot
// frag-order images in ws (1 MB total, resident in every XCD's L2). Each
// wave's long L2-fed middle phase de-synchronizes waves so HBM serves x1/mask
// reads of some waves concurrently with output writes of others.
// ---------------------------------------------------------------------------
__global__ __launch_bounds__(256, 4) void attn_kernel(
    const float* __restrict__ x1, const void* __restrict__ x3,
    const uint8_t* __restrict__ ws, float* __restrict__ out)
{
  const int tid = threadIdx.x, blk = blockIdx.x;
  const int b = blk >> 6, qc = (blk & 63) * 128;
  const int l = tid & 63, w4 = tid >> 6;
  const int q31 = l & 31, hi2 = l >> 5;
  const int byteMode = *(const int*)(ws + WS_FLAG);

  const int q0w = qc + w4 * 32;
  const size_t qrow = (size_t)b * LQ + q0w + q31;   // this lane's q row

  const uint8_t* Mf = ws + WS_MV + (size_t)b * 65536;
  const uint8_t* Vf = Mf + 32768;

  // ---- x1: 16 raw dwordx4 loads per lane ----
  f32x4 xr[16];
  {
    const float* xp = x1 + qrow * H;
    #pragma unroll
    for (int kt = 0; kt < 8; ++kt) {
      xr[2 * kt]     = *(const f32x4*)(xp + kt * 16 + 8 * hi2);
      xr[2 * kt + 1] = *(const f32x4*)(xp + kt * 16 + 8 * hi2 + 4);
    }
  }

  // ---- mask prefetch (byte mode) ----
  uint mu[16];
  if (byteMode) {
    const uint8_t* mp = (const uint8_t*)x3 + qrow * LK;
    #pragma unroll
    for (int jt = 0; jt < 4; ++jt)
      #pragma unroll
      for (int rg = 0; rg < 4; ++rg)
        mu[jt * 4 + rg] = *(const uint*)(mp + jt * 32 + 8 * rg + 4 * hi2);
  }

  // convert x1 to bf16 B-frags
  bf16x8 xbf[8];
  #pragma unroll
  for (int kt = 0; kt < 8; ++kt)
    #pragma unroll
    for (int e = 0; e < 4; ++e) {
      xbf[kt][e]     = (bf16_t)xr[2 * kt][e];
      xbf[kt][e + 4] = (bf16_t)xr[2 * kt + 1][e];
    }

  // ---- S^T = M @ x1^T in two j-tile pairs; pack to bf16 pb-frags ----
  const uint* mrowW = (const uint*)x3 + qrow * LK;
  bf16x8 pb[8];

  #pragma unroll
  for (int half = 0; half < 2; ++half) {
    const int jt0 = half * 2, jt1 = half * 2 + 1;
    f32x16 s0 = zero16(), s1 = zero16();
    __builtin_amdgcn_s_setprio(1);
    #pragma unroll
    for (int kt = 0; kt < 8; ++kt) {
      s0 = MFMA32(*(const bf16x8*)(Mf + (((jt0 * 8 + kt) << 10) | (l << 4))),
                  xbf[kt], s0);
      s1 = MFMA32(*(const bf16x8*)(Mf + (((jt1 * 8 + kt) << 10) | (l << 4))),
                  xbf[kt], s1);
    }
    __builtin_amdgcn_s_setprio(0);

    #pragma unroll
    for (int jj = 0; jj < 2; ++jj) {
      f32x16& sj = jj ? s1 : s0;
      const int jt = half * 2 + jj;
      #pragma unroll
      for (int rg = 0; rg < 4; ++rg) {
        uint m0, m1, m2, m3;
        if (byteMode) {
          uint u = mu[jt * 4 + rg];
          m0 = u & 0xffu; m1 = (u >> 8) & 0xffu; m2 = (u >> 16) & 0xffu; m3 = u >> 24;
        } else {
          uint4 mw = *(const uint4*)(mrowW + jt * 32 + 8 * rg + 4 * hi2);
          m0 = mw.x; m1 = mw.y; m2 = mw.z; m3 = mw.w;
        }
        float p0 = __builtin_amdgcn_exp2f(sj[rg * 4 + 0] * C1);
        float p1 = __builtin_amdgcn_exp2f(sj[rg * 4 + 1] * C1);
        float p2 = __builtin_amdgcn_exp2f(sj[rg * 4 + 2] * C1);
        float p3 = __builtin_amdgcn_exp2f(sj[rg * 4 + 3] * C1);
        sj[rg * 4 + 0] = m0 ? 0.f : p0;
        sj[rg * 4 + 1] = m1 ? 0.f : p1;
        sj[rg * 4 + 2] = m2 ? 0.f : p2;
        sj[rg * 4 + 3] = m3 ? 0.f : p3;
      }

      // P^T B-frags in-register: cvt_pk pairs + permlane32_swap
      #pragma unroll
      for (int h = 0; h < 2; ++h) {
        uint A = pkbf(sj[h * 8 + 0], sj[h * 8 + 1]);
        uint C = pkbf(sj[h * 8 + 2], sj[h * 8 + 3]);
        uint B = pkbf(sj[h * 8 + 4], sj[h * 8 + 5]);
        uint D = pkbf(sj[h * 8 + 6], sj[h * 8 + 7]);
        asm("v_permlane32_swap_b32 %0, %1" : "+v"(A), "+v"(B));
        asm("v_permlane32_swap_b32 %0, %1" : "+v"(C), "+v"(D));
        uintx4 t; t.x = A; t.y = C; t.z = B; t.w = D;
        pb[jt * 2 + h] = __builtin_bit_cast(bf16x8, t);
      }
    }
  }

  // ---- dsum chain + first oc pair (3 independent MFMA chains) ----
  bf16x8 ones1;
  #pragma unroll
  for (int e = 0; e < 8; ++e) ones1[e] = (bf16_t)1.f;

  f32x16 dacc = zero16();
  {
    f32x16 o0 = zero16(), o1 = zero16();
    __builtin_amdgcn_s_setprio(1);
    #pragma unroll
    for (int kt = 0; kt < 8; ++kt) {
      dacc = MFMA32(ones1, pb[kt], dacc);
      o0 = MFMA32(*(const bf16x8*)(Vf + (((0 * 8 + kt) << 10) | (l << 4))), pb[kt], o0);
      o1 = MFMA32(*(const bf16x8*)(Vf + (((1 * 8 + kt) << 10) | (l << 4))), pb[kt], o1);
    }
    __builtin_amdgcn_s_setprio(0);
    const float inv = 1.0f / dacc[0];
    #pragma unroll
    for (int r = 0; r < 16; ++r) {
      const int ibase = (r & 3) + 8 * (r >> 2) + 4 * hi2;
      out[((size_t)b * LK + ibase) * LQ + q0w + q31] = o0[r] * inv;
      out[((size_t)b * LK + 32 + ibase) * LQ + q0w + q31] = o1[r] * inv;
    }
  }

  // ---- second oc pair ----
  {
    f32x16 o2 = zero16(), o3 = zero16();
    __builtin_amdgcn_s_setprio(1);
    #pragma unroll
    for (int kt = 0; kt < 8; ++kt) {
      o2 = MFMA32(*(const bf16x8*)(Vf + (((2 * 8 + kt) << 10) | (l << 4))), pb[kt], o2);
      o3 = MFMA32(*(const bf16x8*)(Vf + (((3 * 8 + kt) << 10) | (l << 4))), pb[kt], o3);
    }
    __builtin_amdgcn_s_setprio(0);
    const float inv = 1.0f / dacc[0];
    #pragma unroll
    for (int r = 0; r < 16; ++r) {
      const int ibase = (r & 3) + 8 * (r >> 2) + 4 * hi2;
      out[((size_t)b * LK + 64 + ibase) * LQ + q0w + q31] = o2[r] * inv;
      out[((size_t)b * LK + 96 + ibase) * LQ + q0w + q31] = o3[r] * inv;
    }
  }
}

extern "C" void kernel_launch(void* const* d_in, const int* in_sizes, int n_in,
                              void* d_out, int out_size, void* d_ws, size_t ws_size,
                              hipStream_t stream) {
  const float* x1 = (const float*)d_in[0];
  const float* x2 = (const float*)d_in[1];
  const void*  x3 = d_in[2];
  const float* wq = (const float*)d_in[3];
  const float* wk = (const float*)d_in[4];
  const float* wv = (const float*)d_in[5];
  uint8_t* ws = (uint8_t*)d_ws;
  float* out = (float*)d_out;

  prep_kernel<<<2 * NB, 512, 0, stream>>>(x2, wq, wk, wv, (const unsigned*)x3, ws);
  attn_kernel<<<NB * (LQ / 128), 256, 0, stream>>>(x1, x3, ws, out);
}

// Round 12
// 50.091 us; speedup vs baseline: 1.0211x; 1.0211x over previous
//
#include <hip/hip_runtime.h>
#include <hip/hip_bf16.h>
#include <stdint.h>

typedef __bf16 bf16_t;
typedef __bf16 bf16x8 __attribute__((ext_vector_type(8)));
typedef float  f32x4  __attribute__((ext_vector_type(4)));
typedef float  f32x16 __attribute__((ext_vector_type(16)));
typedef unsigned int uint;
typedef uint uintx4 __attribute__((ext_vector_type(4)));

#define MFMA16(a,b,c) __builtin_amdgcn_mfma_f32_16x16x32_bf16((a),(b),(c),0,0,0)
#define MFMA32(a,b,c) __builtin_amdgcn_mfma_f32_32x32x16_bf16((a),(b),(c),0,0,0)

constexpr int NB = 16;
constexpr int LQ = 8192;
constexpr int LK = 128;
constexpr int H  = 128;

// log2(e) / sqrt(H): fold softmax scale + exp2 conversion into one multiply
constexpr float C1 = 1.4426950408889634f / 11.313708498984761f;

constexpr size_t WS_FLAG = 0;
// per batch 64KB: [M frag-chunks 32KB | V frag-chunks 32KB]
// chunk (t,kt) at offset ((t*8+kt)<<10); entry for lane l at +l*16:
//   M: M[t*32 + (l&31)][kt*16 + (l>>5)*8 + e], e=0..7  (bf16x8)
//   V: V[t*32 + (l&31)][kt*16 + (l>>5)*8 + e]
constexpr size_t WS_MV   = 1024;

// XOR swizzle for [*][128] bf16 LDS tiles (row stride 256 B)
__device__ __forceinline__ unsigned swz(unsigned row, unsigned byte) {
  return row * 256u + (byte ^ ((row & 15u) << 4));
}

__device__ __forceinline__ bf16x8 cvt_frag(const float* p) {
  f32x4 u0 = *(const f32x4*)p;
  f32x4 u1 = *(const f32x4*)(p + 4);
  bf16x8 v;
  #pragma unroll
  for (int e = 0; e < 4; ++e) { v[e] = (bf16_t)u0[e]; v[e + 4] = (bf16_t)u1[e]; }
  return v;
}

__device__ __forceinline__ f32x16 zero16() {
  f32x16 z;
  #pragma unroll
  for (int i = 0; i < 16; ++i) z[i] = 0.f;
  return z;
}

// v_cvt_pk_bf16_f32: lo = bf16(a), hi = bf16(b)
__device__ __forceinline__ uint pkbf(float a, float b) {
  uint d;
  asm("v_cvt_pk_bf16_f32 %0, %1, %2" : "=v"(d) : "v"(a), "v"(b));
  return d;
}

// ---------------------------------------------------------------------------
// prep (32 blocks): block 2b   -> M_b = x2_b @ (wq^T wk)  (frag-order to ws)
//                   block 2b+1 -> V_b = x2_b @ wv^T       (frag-order to ws)
// (unchanged from r11, validated)
// ---------------------------------------------------------------------------
__global__ __launch_bounds__(512) void prep_kernel(
    const float* __restrict__ x2, const float* __restrict__ wq,
    const float* __restrict__ wk, const float* __restrict__ wv,
    const unsigned* __restrict__ x3w, uint8_t* __restrict__ ws)
{
  __shared__ uint8_t sP[131072];  // [wqT 32K | wkT 32K | W2T lin 32K | out 32K]
  __shared__ int sF32, sBig;
  const int tid = threadIdx.x;
  const int b = blockIdx.x >> 1, which = blockIdx.x & 1;
  const int l = tid & 63, w = tid >> 6, q31 = l & 31, hi2 = l >> 5;
  uint8_t* sOut = sP + 98304;

  if (which == 0) {
    if (blockIdx.x == 0) {
      // mask dtype probe over first 2048 words of x3:
      // int32 bool -> words in {0,1}; uint8 bool -> words like 0x01010101 (>1);
      // f32 bool -> words in {0, 0x3f800000}
      if (tid == 0) { sF32 = 0; sBig = 0; }
      __syncthreads();
      int f = 0, g = 0;
      #pragma unroll
      for (int j = 0; j < 4; ++j) {
        unsigned v = x3w[tid * 4 + j];
        if (v == 0x3f800000u) f = 1;
        else if (v > 1u) g = 1;
      }
      if (f) sF32 = 1;
      if (g) sBig = 1;
      __syncthreads();
      if (tid == 0) *(int*)(ws + WS_FLAG) = (sF32 == 0 && sBig == 1) ? 1 : 0;
    }

    // stage wqT / wkT swizzled
    {
      const int row = tid >> 2, c0 = (tid & 3) * 32;
      #pragma unroll
      for (int wh = 0; wh < 2; ++wh) {
        const float* W = wh ? wk : wq;
        uint8_t* dst = sP + wh * 32768;
        const float* s = W + row * H + c0;
        #pragma unroll
        for (int j = 0; j < 32; ++j)
          *(bf16_t*)(dst + swz(c0 + j, row * 2)) = (bf16_t)s[j];
      }
    }
    __syncthreads();

    // W2T[i][j] = sum_k wq[k][i] wk[k][j]  -> LDS linear [128][128] bf16
    {
      const int lo = l & 15, hi = l >> 4;
      bf16x8 a4[4];
      #pragma unroll
      for (int kk = 0; kk < 4; ++kk)
        a4[kk] = *(const bf16x8*)(sP + swz(16 * w + lo, kk * 64 + hi * 16));
      bf16_t* W2T = (bf16_t*)(sP + 65536);
      #pragma unroll
      for (int t = 0; t < 8; ++t) {
        f32x4 c = {0.f, 0.f, 0.f, 0.f};
        #pragma unroll
        for (int kk = 0; kk < 4; ++kk)
          c = MFMA16(a4[kk], *(const bf16x8*)(sP + 32768 + swz(16 * t + lo, kk * 64 + hi * 16)), c);
        #pragma unroll
        for (int r = 0; r < 4; ++r)
          W2T[(16 * w + hi * 4 + r) * H + 16 * t + lo] = (bf16_t)c[r];
      }
    }
    __syncthreads();

    // M build
    if (w < 4) {
      const int wb = w;
      bf16x8 axf[8];
      const float* x2r = x2 + ((size_t)b * LK + 32 * wb + q31) * H;
      #pragma unroll
      for (int kt = 0; kt < 8; ++kt)
        axf[kt] = cvt_frag(x2r + kt * 16 + 8 * hi2);
      const bf16_t* W2Tl = (const bf16_t*)(sP + 65536);
      #pragma unroll
      for (int nt = 0; nt < 4; ++nt) {
        f32x16 c = zero16();
        #pragma unroll
        for (int kt = 0; kt < 8; ++kt)
          c = MFMA32(axf[kt],
                     *(const bf16x8*)(W2Tl + (size_t)(nt * 32 + q31) * H + kt * 16 + 8 * hi2), c);
        #pragma unroll
        for (int r = 0; r < 16; ++r)
          *(bf16_t*)(sOut + swz(32 * wb + (r & 3) + 8 * (r >> 2) + 4 * hi2,
                                (nt * 32 + q31) * 2)) = (bf16_t)c[r];
      }
    }
  } else {
    // V build
    if (w < 4) {
      const int wb = w;
      bf16x8 axf[8];
      const float* x2r = x2 + ((size_t)b * LK + 32 * wb + q31) * H;
      #pragma unroll
      for (int kt = 0; kt < 8; ++kt)
        axf[kt] = cvt_frag(x2r + kt * 16 + 8 * hi2);
      #pragma unroll
      for (int nt = 0; nt < 4; ++nt) {
        f32x16 c = zero16();
        #pragma unroll
        for (int kt = 0; kt < 8; ++kt)
          c = MFMA32(axf[kt],
                     cvt_frag(wv + (size_t)(nt * 32 + q31) * H + kt * 16 + 8 * hi2), c);
        #pragma unroll
        for (int r = 0; r < 16; ++r)
          *(bf16_t*)(sOut + swz(32 * wb + (r & 3) + 8 * (r >> 2) + 4 * hi2,
                                (nt * 32 + q31) * 2)) = (bf16_t)c[r];
      }
    }
  }
  __syncthreads();

  // repack swizzled image -> fragment-major chunks in ws.
  {
    uint8_t* dst = ws + WS_MV + (size_t)b * 65536 + (size_t)which * 32768;
    #pragma unroll
    for (int pass = 0; pass < 4; ++pass) {
      const int idx = tid + pass * 512;         // 0..2047
      const int chunk = idx >> 6, le = idx & 63;
      const int t4 = chunk >> 3, kt = chunk & 7;
      bf16x8 v = *(const bf16x8*)(sOut + swz(t4 * 32 + (le & 31),
                                             kt * 32 + (le >> 5) * 16));
      *(bf16x8*)(dst + (size_t)idx * 16) = v;
    }
  }
}

// ---------------------------------------------------------------------------
// Main fused kernel — r11 core + COALESCED x1 via LDS staging.
// Block = 256 threads = 4 waves, 128 q-rows, grid 1024. The block's x1 tile
// (128x128 f32) is staged with fully-dense loads (4 KB consecutive per
// instruction, 16 iters/thread), converted to bf16, stored swizzled in 32 KB
// LDS; B-frags then come from conflict-free ds_read_b128 (r6-r8 validated
// pattern). This removes the 64-lines-per-instruction divergent x1 reads
// that every prior round shared. M/V frags still stream from L2 (r11 path).
// LDS 32 KB -> 5 blocks/CU = 20 waves/CU.
// ---------------------------------------------------------------------------
__global__ __launch_bounds__(256, 4) void attn_kernel(
    const float* __restrict__ x1, const void* __restrict__ x3,
    const uint8_t* __restrict__ ws, float* __restrict__ out)
{
  __shared__ uint8_t sX[32768];   // x1 tile [128 rows][128] bf16, swizzled

  const int tid = threadIdx.x, blk = blockIdx.x;
  const int b = blk >> 6, qc = (blk & 63) * 128;
  const int l = tid & 63, w4 = tid >> 6;
  const int q31 = l & 31, hi2 = l >> 5;
  const int byteMode = *(const int*)(ws + WS_FLAG);

  const int q0w = qc + w4 * 32;
  const size_t qrow = (size_t)b * LQ + q0w + q31;   // this lane's q row

  const uint8_t* Mf = ws + WS_MV + (size_t)b * 65536;
  const uint8_t* Vf = Mf + 32768;

  // ---- mask prefetch (byte mode): 1 line per lane-row, L1-served after 1st ----
  uint mu[16];
  if (byteMode) {
    const uint8_t* mp = (const uint8_t*)x3 + qrow * LK;
    #pragma unroll
    for (int jt = 0; jt < 4; ++jt)
      #pragma unroll
      for (int rg = 0; rg < 4; ++rg)
        mu[jt * 4 + rg] = *(const uint*)(mp + jt * 32 + 8 * rg + 4 * hi2);
  }

  // ---- stage x1 tile -> LDS: fully-coalesced (4 KB/instr), f32 -> bf16 ----
  {
    const float* xbase = x1 + ((size_t)b * LQ + qc) * H;
    #pragma unroll
    for (int it = 0; it < 16; ++it) {
      const int fidx = (it * 256 + tid) * 4;          // flat float index
      f32x4 v = *(const f32x4*)(xbase + fidx);
      const int row = fidx >> 7;                      // 128 floats per row
      const int colb = (fidx & 127) * 2;              // byte col in bf16 tile
      uint2 dw;
      dw.x = pkbf(v[0], v[1]);
      dw.y = pkbf(v[2], v[3]);
      *(uint2*)(sX + row * 256 + (colb ^ ((row & 15) << 4))) = dw;
    }
  }
  __syncthreads();

  // ---- x1 B-frags from LDS (conflict-free swizzled ds_read_b128) ----
  bf16x8 xbf[8];
  #pragma unroll
  for (int kt = 0; kt < 8; ++kt)
    xbf[kt] = *(const bf16x8*)(sX + swz(w4 * 32 + q31, kt * 32 + hi2 * 16));

  // ---- S^T = M @ x1^T in two j-tile pairs; pack to bf16 pb-frags ----
  const uint* mrowW = (const uint*)x3 + qrow * LK;
  bf16x8 pb[8];

  #pragma unroll
  for (int half = 0; half < 2; ++half) {
    const int jt0 = half * 2, jt1 = half * 2 + 1;
    f32x16 s0 = zero16(), s1 = zero16();
    __builtin_amdgcn_s_setprio(1);
    #pragma unroll
    for (int kt = 0; kt < 8; ++kt) {
      s0 = MFMA32(*(const bf16x8*)(Mf + (((jt0 * 8 + kt) << 10) | (l << 4))),
                  xbf[kt], s0);
      s1 = MFMA32(*(const bf16x8*)(Mf + (((jt1 * 8 + kt) << 10) | (l << 4))),
                  xbf[kt], s1);
    }
    __builtin_amdgcn_s_setprio(0);

    #pragma unroll
    for (int jj = 0; jj < 2; ++jj) {
      f32x16& sj = jj ? s1 : s0;
      const int jt = half * 2 + jj;
      #pragma unroll
      for (int rg = 0; rg < 4; ++rg) {
        uint m0, m1, m2, m3;
        if (byteMode) {
          uint u = mu[jt * 4 + rg];
          m0 = u & 0xffu; m1 = (u >> 8) & 0xffu; m2 = (u >> 16) & 0xffu; m3 = u >> 24;
        } else {
          uint4 mw = *(const uint4*)(mrowW + jt * 32 + 8 * rg + 4 * hi2);
          m0 = mw.x; m1 = mw.y; m2 = mw.z; m3 = mw.w;
        }
        float p0 = __builtin_amdgcn_exp2f(sj[rg * 4 + 0] * C1);
        float p1 = __builtin_amdgcn_exp2f(sj[rg * 4 + 1] * C1);
        float p2 = __builtin_amdgcn_exp2f(sj[rg * 4 + 2] * C1);
        float p3 = __builtin_amdgcn_exp2f(sj[rg * 4 + 3] * C1);
        sj[rg * 4 + 0] = m0 ? 0.f : p0;
        sj[rg * 4 + 1] = m1 ? 0.f : p1;
        sj[rg * 4 + 2] = m2 ? 0.f : p2;
        sj[rg * 4 + 3] = m3 ? 0.f : p3;
      }

      // P^T B-frags in-register: cvt_pk pairs + permlane32_swap
      #pragma unroll
      for (int h = 0; h < 2; ++h) {
        uint A = pkbf(sj[h * 8 + 0], sj[h * 8 + 1]);
        uint C = pkbf(sj[h * 8 + 2], sj[h * 8 + 3]);
        uint B = pkbf(sj[h * 8 + 4], sj[h * 8 + 5]);
        uint D = pkbf(sj[h * 8 + 6], sj[h * 8 + 7]);
        asm("v_permlane32_swap_b32 %0, %1" : "+v"(A), "+v"(B));
        asm("v_permlane32_swap_b32 %0, %1" : "+v"(C), "+v"(D));
        uintx4 t; t.x = A; t.y = C; t.z = B; t.w = D;
        pb[jt * 2 + h] = __builtin_bit_cast(bf16x8, t);
      }
    }
  }

  // ---- dsum chain + first oc pair (3 independent MFMA chains) ----
  bf16x8 ones1;
  #pragma unroll
  for (int e = 0; e < 8; ++e) ones1[e] = (bf16_t)1.f;

  f32x16 dacc = zero16();
  {
    f32x16 o0 = zero16(), o1 = zero16();
    __builtin_amdgcn_s_setprio(1);
    #pragma unroll
    for (int kt = 0; kt < 8; ++kt) {
      dacc = MFMA32(ones1, pb[kt], dacc);
      o0 = MFMA32(*(const bf16x8*)(Vf + (((0 * 8 + kt) << 10) | (l << 4))), pb[kt], o0);
      o1 = MFMA32(*(const bf16x8*)(Vf + (((1 * 8 + kt) << 10) | (l << 4))), pb[kt], o1);
    }
    __builtin_amdgcn_s_setprio(0);
    const float inv = 1.0f / dacc[0];
    #pragma unroll
    for (int r = 0; r < 16; ++r) {
      const int ibase = (r & 3) + 8 * (r >> 2) + 4 * hi2;
      out[((size_t)b * LK + ibase) * LQ + q0w + q31] = o0[r] * inv;
      out[((size_t)b * LK + 32 + ibase) * LQ + q0w + q31] = o1[r] * inv;
    }
  }

  // ---- second oc pair ----
  {
    f32x16 o2 = zero16(), o3 = zero16();
    __builtin_amdgcn_s_setprio(1);
    #pragma unroll
    for (int kt = 0; kt < 8; ++kt) {
      o2 = MFMA32(*(const bf16x8*)(Vf + (((2 * 8 + kt) << 10) | (l << 4))), pb[kt], o2);
      o3 = MFMA32(*(const bf16x8*)(Vf + (((3 * 8 + kt) << 10) | (l << 4))), pb[kt], o3);
    }
    __builtin_amdgcn_s_setprio(0);
    const float inv = 1.0f / dacc[0];
    #pragma unroll
    for (int r = 0; r < 16; ++r) {
      const int ibase = (r & 3) + 8 * (r >> 2) + 4 * hi2;
      out[((size_t)b * LK + 64 + ibase) * LQ + q0w + q31] = o2[r] * inv;
      out[((size_t)b * LK + 96 + ibase) * LQ + q0w + q31] = o3[r] * inv;
    }
  }
}

extern "C" void kernel_launch(void* const* d_in, const int* in_sizes, int n_in,
                              void* d_out, int out_size, void* d_ws, size_t ws_size,
                              hipStream_t stream) {
  const float* x1 = (const float*)d_in[0];
  const float* x2 = (const float*)d_in[1];
  const void*  x3 = d_in[2];
  const float* wq = (const float*)d_in[3];
  const float* wk = (const float*)d_in[4];
  const float* wv = (const float*)d_in[5];
  uint8_t* ws = (uint8_t*)d_ws;
  float* out = (float*)d_out;

  prep_kernel<<<2 * NB, 512, 0, stream>>>(x2, wq, wk, wv, (const unsigned*)x3, ws);
  attn_kernel<<<NB * (LQ / 128), 256, 0, stream>>>(x1, x3, ws, out);
}